// Round 3
// baseline (542.594 us; speedup 1.0000x reference)
//
#include <hip/hip_runtime.h>

// ExplodedLogit: out (512, 1 + 512*512) fp32.
//   scores = x @ W.T + b            (512,)
//   idx    = argmax(scores)
//   out[i][0]             = scores[i]
//   out[i][1 + r*512 + j] = scores[i] * (j==idx ? MASK_VAL : 1.0f)
//
// R6 == R5 resubmitted (R5 bench was an infra failure, never measured).
// Memset-identical fill. R4 (flat, branchy loop body w/ dependent scores
// reloads) = 3.3 TB/s; rocclr poison fill = 6.28 TB/s on the SAME buffer.
// This version removes ALL in-loop work:
//  - per row r, the 16B-aligned f4 interior [A_r, T_r) is 65535-65536 f4s
//    -> exactly 64 blocks x 1024 f4 (one ≤1-f4 guard on the last chunk)
//  - block-uniform scores[row] + idx -> s_load once per block
//  - thread store stride = 1024 floats ≡ 0 mod 512 pattern period ->
//    float4 val computed ONCE per thread (~20 VALU), then 4 pure
//    dwordx4 stores
//  - col 0 and the ≤4 unaligned row-edge floats are written by the
//    argmax kernel (512 threads x ≤5 scalar stores)

#define TRACKS 512
#define FEATURES 256
#define ROWSTRIDE 262145LL          // 1 + 512*512
#define MASK_VAL (-105.918914f)     // float32(log(1e-46))
#define BPR 64                      // blocks per row -> 32768 blocks total

typedef float vf4 __attribute__((ext_vector_type(4)));

// ---- kernel 1: one wave per row dot-product ----
__global__ __launch_bounds__(64) void scores_kernel(
    const float* __restrict__ x, const float* __restrict__ W,
    const float* __restrict__ b, float* __restrict__ scores) {
  int row = blockIdx.x;
  int lane = threadIdx.x;  // 0..63
  const float4* xr = (const float4*)(x + row * FEATURES);
  const float4* wr = (const float4*)W;
  float4 xv = xr[lane];
  float4 wv = wr[lane];
  float s = xv.x * wv.x + xv.y * wv.y + xv.z * wv.z + xv.w * wv.w;
#pragma unroll
  for (int off = 32; off; off >>= 1) s += __shfl_down(s, off);
  if (lane == 0) scores[row] = s + b[0];
}

// ---- kernel 2: argmax + col-0 + unaligned row-edge floats ----
// One block, 512 threads. Thread t owns row t's edges:
//   col 0 at F = t*ROWSTRIDE
//   leading floats [F+1, A)  where A = (F+4) & ~3   (0..3 floats)
//   trailing floats [T, F+ROWSTRIDE) where T = (F+ROWSTRIDE) & ~3 (0..3)
__global__ __launch_bounds__(512) void argmax_edges_kernel(
    const float* __restrict__ scores, int* __restrict__ idx_out,
    float* __restrict__ out) {
  __shared__ float svals[TRACKS];
  __shared__ int sidx[TRACKS];
  int t = threadIdx.x;
  float s = scores[t];
  svals[t] = s;
  sidx[t] = t;
  __syncthreads();
  for (int off = 256; off; off >>= 1) {
    if (t < off) {
      float v2 = svals[t + off];
      int i2 = sidx[t + off];
      if (v2 > svals[t] || (v2 == svals[t] && i2 < sidx[t])) {
        svals[t] = v2;
        sidx[t] = i2;
      }
    }
    __syncthreads();
  }
  if (t == 0) idx_out[0] = sidx[0];
  int idx = sidx[0];  // valid: last loop iteration ended with __syncthreads

  float sm = s * MASK_VAL;
  long long F = (long long)t * ROWSTRIDE;
  out[F] = s;  // column 0
  long long A = (F + 4) & ~3LL;
  for (long long p = F + 1; p < A; ++p) {
    int j = (int)(p - F - 1) & 511;
    out[p] = (j == idx) ? sm : s;
  }
  long long T = (F + ROWSTRIDE) & ~3LL;
  for (long long p = T; p < F + ROWSTRIDE; ++p) {
    int j = (int)(p - F - 1) & 511;
    out[p] = (j == idx) ? sm : s;
  }
}

// ---- kernel 3: pure-store fill of each row's aligned f4 interior ----
__global__ __launch_bounds__(256) void fill_kernel(
    const float* __restrict__ scores, const int* __restrict__ idxp,
    float* __restrict__ out) {
  int row = blockIdx.x >> 6;      // / BPR
  int chunk = blockIdx.x & (BPR - 1);
  int t = threadIdx.x;

  float s = scores[row];          // block-uniform -> scalar load
  int idx = *idxp;                // block-uniform -> scalar load
  float sm = s * MASK_VAL;

  long long F = (long long)row * ROWSTRIDE;
  long long A4 = (F + 4) >> 2;                 // first aligned f4 of interior
  long long T4 = (F + ROWSTRIDE) >> 2;         // one past last aligned f4
  long long p4 = A4 + (long long)chunk * 1024 + t;

  // pattern position of this thread's f4; invariant across the 4 stores
  // (stride 256 f4 = 1024 floats ≡ 0 mod 512)
  int j0 = (int)((4 * p4 - F - 1) & 511);
  vf4 val;
  val.x = (j0 == idx) ? sm : s;
  val.y = (((j0 + 1) & 511) == idx) ? sm : s;
  val.z = (((j0 + 2) & 511) == idx) ? sm : s;
  val.w = (((j0 + 3) & 511) == idx) ? sm : s;

  vf4* outv = (vf4*)out;
#pragma unroll
  for (int k = 0; k < 4; ++k) {
    long long p = p4 + k * 256;
    if (p < T4) outv[p] = val;   // guard trims ≤1 f4 on the last chunk
  }
}

extern "C" void kernel_launch(void* const* d_in, const int* in_sizes, int n_in,
                              void* d_out, int out_size, void* d_ws,
                              size_t ws_size, hipStream_t stream) {
  const float* x = (const float*)d_in[0];
  const float* W = (const float*)d_in[1];
  const float* b = (const float*)d_in[2];
  float* out = (float*)d_out;

  float* scores = (float*)d_ws;              // 512 floats
  int* idx = (int*)((float*)d_ws + TRACKS);  // 1 int

  scores_kernel<<<TRACKS, 64, 0, stream>>>(x, W, b, scores);
  argmax_edges_kernel<<<1, TRACKS, 0, stream>>>(scores, idx, out);
  fill_kernel<<<TRACKS * BPR, 256, 0, stream>>>(scores, idx, out);
}